// Round 1
// baseline (314.987 us; speedup 1.0000x reference)
//
#include <hip/hip_runtime.h>

// 2-layer GCN (PyG GCNConv semantics) on MI355X.
// Strategy: build CSR-by-dst once (shared by both layers), then per layer:
//   dense transform (x@W) -> gather over incoming edges (wave per node,
//   lane = channel) -> +bias, ReLU.
// Avoids 102M fp32 scatter atomics; only 1.6M int atomics for CSR build.

constexpr int NN = 50000;   // nodes
constexpr int NE = 800000;  // edges

#define ALIGN_UP(x, a) (((x) + (a) - 1) / (a) * (a))

__global__ void count_deg(const int* __restrict__ dst, int* __restrict__ cnt) {
    int i = blockIdx.x * 256 + threadIdx.x;
    if (i < NE) atomicAdd(&cnt[dst[i]], 1);
}

// Per-256-chunk exclusive scan of cnt into off; block totals into bsum.
// Also computes dinv[i] = rsqrt(indeg+1) (self-loop included -> always > 0).
__global__ void scanA(const int* __restrict__ cnt, float* __restrict__ dinv,
                      int* __restrict__ off, int* __restrict__ bsum) {
    __shared__ int s[256];
    int tid = threadIdx.x;
    int i = blockIdx.x * 256 + tid;
    int v = (i < NN) ? cnt[i] : 0;
    if (i < NN) dinv[i] = rsqrtf((float)(v + 1));
    s[tid] = v;
    __syncthreads();
#pragma unroll
    for (int o = 1; o < 256; o <<= 1) {
        int t = (tid >= o) ? s[tid - o] : 0;
        __syncthreads();
        s[tid] += t;
        __syncthreads();
    }
    if (i < NN) off[i] = s[tid] - v;  // exclusive within block
    if (tid == 255) bsum[blockIdx.x] = s[255];
}

__global__ void scanB(const int* __restrict__ bsum, int* __restrict__ bofs, int nb) {
    __shared__ int s[256];
    int tid = threadIdx.x;
    int v = (tid < nb) ? bsum[tid] : 0;
    s[tid] = v;
    __syncthreads();
#pragma unroll
    for (int o = 1; o < 256; o <<= 1) {
        int t = (tid >= o) ? s[tid - o] : 0;
        __syncthreads();
        s[tid] += t;
        __syncthreads();
    }
    bofs[tid] = s[tid] - v;
}

__global__ void scanC(int* __restrict__ off, const int* __restrict__ bofs,
                      int* __restrict__ cursor) {
    int i = blockIdx.x * 256 + threadIdx.x;
    if (i < NN) {
        int o = off[i] + bofs[blockIdx.x];
        off[i] = o;
        cursor[i] = o;
    }
    if (i == 0) off[NN] = NE;
}

// Bucket-fill CSR: csr[pos] = {src, bits(norm)}; norm = dinv[s]*dinv[d].
__global__ void fill_csr(const int* __restrict__ src, const int* __restrict__ dst,
                         const float* __restrict__ dinv, int* __restrict__ cursor,
                         int2* __restrict__ csr) {
    int i = blockIdx.x * 256 + threadIdx.x;
    if (i < NE) {
        int s = src[i], d = dst[i];
        int pos = atomicAdd(&cursor[d], 1);
        csr[pos] = make_int2(s, __float_as_int(dinv[s] * dinv[d]));
    }
}

// h = x @ W1  (IN_DIM=4 -> 64). One thread per (node, col).
__global__ void xform1(const float* __restrict__ x, const float* __restrict__ W1,
                       float* __restrict__ h) {
    int gid = blockIdx.x * 256 + threadIdx.x;
    int node = gid >> 6, c = gid & 63;
    if (node >= NN) return;
    float4 xv = *reinterpret_cast<const float4*>(x + node * 4);
    float acc = xv.x * W1[c];
    acc = fmaf(xv.y, W1[64 + c], acc);
    acc = fmaf(xv.z, W1[128 + c], acc);
    acc = fmaf(xv.w, W1[192 + c], acc);
    h[gid] = acc;
}

// h = y @ W2  (64 -> 64). One thread per (node, col); W2 is 16KB -> L1-hot.
__global__ void xform2(const float* __restrict__ y, const float* __restrict__ W2,
                       float* __restrict__ h) {
    int gid = blockIdx.x * 256 + threadIdx.x;
    int node = gid >> 6, c = gid & 63;
    float acc = 0.f;
    const float* yr = y + node * 64;
#pragma unroll
    for (int k4 = 0; k4 < 16; ++k4) {
        float4 yv = *reinterpret_cast<const float4*>(yr + k4 * 4);
        acc = fmaf(yv.x, W2[(k4 * 4 + 0) * 64 + c], acc);
        acc = fmaf(yv.y, W2[(k4 * 4 + 1) * 64 + c], acc);
        acc = fmaf(yv.z, W2[(k4 * 4 + 2) * 64 + c], acc);
        acc = fmaf(yv.w, W2[(k4 * 4 + 3) * 64 + c], acc);
    }
    h[gid] = acc;
}

// out[n][lane] = relu( h[n]*dinv[n]^2 + sum_{e: s->n} h[s]*norm_e + bias ).
// One wave per node (lane = channel); coalesced 256B row reads of h[src].
__global__ void gather(const float* __restrict__ h, const int* __restrict__ off,
                       const int2* __restrict__ csr, const float* __restrict__ dinv,
                       const float* __restrict__ bias, float* __restrict__ out) {
    int gid = blockIdx.x * 256 + threadIdx.x;
    int node = gid >> 6;
    int lane = threadIdx.x & 63;
    float di = dinv[node];
    float acc = h[gid] * di * di;  // self-loop
    int j = off[node], end = off[node + 1];
    for (; j + 1 < end; j += 2) {
        int2 e0 = csr[j];
        int2 e1 = csr[j + 1];
        float v0 = h[e0.x * 64 + lane];
        float v1 = h[e1.x * 64 + lane];
        acc = fmaf(v0, __int_as_float(e0.y), acc);
        acc = fmaf(v1, __int_as_float(e1.y), acc);
    }
    if (j < end) {
        int2 e0 = csr[j];
        acc = fmaf(h[e0.x * 64 + lane], __int_as_float(e0.y), acc);
    }
    out[gid] = fmaxf(acc + bias[lane], 0.f);
}

extern "C" void kernel_launch(void* const* d_in, const int* in_sizes, int n_in,
                              void* d_out, int out_size, void* d_ws, size_t ws_size,
                              hipStream_t stream) {
    const float* x  = (const float*)d_in[0];
    const int*   ei = (const int*)d_in[1];   // [2, NE] row-major: src row then dst row
    const float* W1 = (const float*)d_in[2];
    const float* b1 = (const float*)d_in[3];
    const float* W2 = (const float*)d_in[4];
    const float* b2 = (const float*)d_in[5];
    float* out = (float*)d_out;
    const int* src = ei;
    const int* dst = ei + NE;

    char* w = (char*)d_ws;
    auto take = [&](size_t bytes) { char* p = w; w += ALIGN_UP(bytes, 256); return p; };
    int*   cnt    = (int*)  take((size_t)NN * 4);
    float* dinv   = (float*)take((size_t)NN * 4);
    int*   off    = (int*)  take((size_t)(NN + 1) * 4);
    int*   cursor = (int*)  take((size_t)NN * 4);
    int*   bsum   = (int*)  take(256 * 4);
    int*   bofs   = (int*)  take(256 * 4);
    int2*  csr    = (int2*) take((size_t)NE * 8);
    float* h      = (float*)take((size_t)NN * 64 * 4);

    const int NB_SCAN = (NN + 255) / 256;      // 196 blocks of 256
    const int NB_EDGE = (NE + 255) / 256;      // 3125
    const int NB_NODE = (NN * 64) / 256;       // 12500 (exact)

    hipMemsetAsync(cnt, 0, (size_t)NN * 4, stream);
    count_deg<<<NB_EDGE, 256, 0, stream>>>(dst, cnt);
    scanA<<<NB_SCAN, 256, 0, stream>>>(cnt, dinv, off, bsum);
    scanB<<<1, 256, 0, stream>>>(bsum, bofs, NB_SCAN);
    scanC<<<NB_SCAN, 256, 0, stream>>>(off, bofs, cursor);
    fill_csr<<<NB_EDGE, 256, 0, stream>>>(src, dst, dinv, cursor, csr);

    // Layer 1: x@W1 -> gather -> out (used as layer-1 activation buffer)
    xform1<<<NB_NODE, 256, 0, stream>>>(x, W1, h);
    gather<<<NB_NODE, 256, 0, stream>>>(h, off, csr, dinv, b1, out);

    // Layer 2: out@W2 -> gather -> out (final)
    xform2<<<NB_NODE, 256, 0, stream>>>(out, W2, h);
    gather<<<NB_NODE, 256, 0, stream>>>(h, off, csr, dinv, b2, out);
}

// Round 2
// 230.469 us; speedup vs baseline: 1.3667x; 1.3667x over previous
//
#include <hip/hip_runtime.h>

// 2-layer GCN (PyG GCNConv semantics) on MI355X, round 2.
// Key algebraic move: aggregate-then-transform (A(xW) == (Ax)W), so layer 1
// gathers 4 channels (not 64) and layer 2 fuses the 64x64 transform into the
// gather epilogue via a 1KB LDS row stage. CSR-by-dst built once, shared.

constexpr int NN = 50000;   // nodes
constexpr int NE = 800000;  // edges

#define ALIGN_UP(x, a) (((x) + (a) - 1) / (a) * (a))

__global__ void count_deg(const int* __restrict__ dst, int* __restrict__ cnt) {
    int i = blockIdx.x * 256 + threadIdx.x;
    if (i < NE) atomicAdd(&cnt[dst[i]], 1);
}

// Per-256-chunk exclusive scan of cnt into off; block totals into bsum.
// Also dinv[i] = rsqrt(indeg+1) (self-loop included -> always > 0).
__global__ void scanA(const int* __restrict__ cnt, float* __restrict__ dinv,
                      int* __restrict__ off, int* __restrict__ bsum) {
    __shared__ int s[256];
    int tid = threadIdx.x;
    int i = blockIdx.x * 256 + tid;
    int v = (i < NN) ? cnt[i] : 0;
    if (i < NN) dinv[i] = rsqrtf((float)(v + 1));
    s[tid] = v;
    __syncthreads();
#pragma unroll
    for (int o = 1; o < 256; o <<= 1) {
        int t = (tid >= o) ? s[tid - o] : 0;
        __syncthreads();
        s[tid] += t;
        __syncthreads();
    }
    if (i < NN) off[i] = s[tid] - v;  // exclusive within block
    if (tid == 255) bsum[blockIdx.x] = s[255];
}

__global__ void scanB(const int* __restrict__ bsum, int* __restrict__ bofs, int nb) {
    __shared__ int s[256];
    int tid = threadIdx.x;
    int v = (tid < nb) ? bsum[tid] : 0;
    s[tid] = v;
    __syncthreads();
#pragma unroll
    for (int o = 1; o < 256; o <<= 1) {
        int t = (tid >= o) ? s[tid - o] : 0;
        __syncthreads();
        s[tid] += t;
        __syncthreads();
    }
    bofs[tid] = s[tid] - v;
}

__global__ void scanC(int* __restrict__ off, const int* __restrict__ bofs,
                      int* __restrict__ cursor) {
    int i = blockIdx.x * 256 + threadIdx.x;
    if (i < NN) {
        int o = off[i] + bofs[blockIdx.x];
        off[i] = o;
        cursor[i] = o;
    }
    if (i == 0) off[NN] = NE;
}

// csr[pos] = {src, bits(norm)}; norm = dinv[s]*dinv[d].
__global__ void fill_csr(const int* __restrict__ src, const int* __restrict__ dst,
                         const float* __restrict__ dinv, int* __restrict__ cursor,
                         int2* __restrict__ csr) {
    int i = blockIdx.x * 256 + threadIdx.x;
    if (i < NE) {
        int s = src[i], d = dst[i];
        int pos = atomicAdd(&cursor[d], 1);
        csr[pos] = make_int2(s, __float_as_int(dinv[s] * dinv[d]));
    }
}

// Layer 1 fused: agg4 = A_hat x  (wave per node, lane per edge, butterfly
// reduce), then h1[n][lane] = relu(agg4 . W1[:,lane] + b1[lane]).
// 50000 nodes = 12500 blocks x 4 waves exactly.
__global__ __launch_bounds__(256) void gcn_layer1(
        const float* __restrict__ x, const int* __restrict__ off,
        const int2* __restrict__ csr, const float* __restrict__ dinv,
        const float* __restrict__ W1, const float* __restrict__ b1,
        float* __restrict__ h1) {
    int wv = threadIdx.x >> 6, lane = threadIdx.x & 63;
    int node = blockIdx.x * 4 + wv;
    float ax = 0.f, ay = 0.f, az = 0.f, aw = 0.f;
    int end = off[node + 1];
    for (int j = off[node] + lane; j < end; j += 64) {
        int2 e = csr[j];
        float4 xv = *reinterpret_cast<const float4*>(x + e.x * 4);
        float nrm = __int_as_float(e.y);
        ax = fmaf(xv.x, nrm, ax);
        ay = fmaf(xv.y, nrm, ay);
        az = fmaf(xv.z, nrm, az);
        aw = fmaf(xv.w, nrm, aw);
    }
#pragma unroll
    for (int o = 32; o >= 1; o >>= 1) {
        ax += __shfl_xor(ax, o);
        ay += __shfl_xor(ay, o);
        az += __shfl_xor(az, o);
        aw += __shfl_xor(aw, o);
    }
    float di = dinv[node];
    float sl = di * di;  // self-loop norm
    float4 xs = *reinterpret_cast<const float4*>(x + node * 4);
    ax = fmaf(xs.x, sl, ax);
    ay = fmaf(xs.y, sl, ay);
    az = fmaf(xs.z, sl, az);
    aw = fmaf(xs.w, sl, aw);
    float o = b1[lane];
    o = fmaf(ax, W1[lane], o);
    o = fmaf(ay, W1[64 + lane], o);
    o = fmaf(az, W1[128 + lane], o);
    o = fmaf(aw, W1[192 + lane], o);
    h1[node * 64 + lane] = fmaxf(o, 0.f);
}

// Layer 2 fused: agg[n][lane] = (A_hat h1)[n][lane] (wave per node, lane =
// channel, unroll-8 for MLP), stage row in LDS, then
// out[n][lane] = relu(agg_row . W2[:,lane] + b2[lane]).
__global__ __launch_bounds__(256) void gcn_layer2(
        const float* __restrict__ h, const int* __restrict__ off,
        const int2* __restrict__ csr, const float* __restrict__ dinv,
        const float* __restrict__ W2, const float* __restrict__ b2,
        float* __restrict__ out) {
    __shared__ float srow[4][64];
    int gid = blockIdx.x * 256 + threadIdx.x;
    int node = gid >> 6;
    int lane = threadIdx.x & 63, wv = threadIdx.x >> 6;
    float di = dinv[node];
    float acc = h[gid] * di * di;  // self-loop
    int j = off[node], end = off[node + 1];
    for (; j + 7 < end; j += 8) {
        int2 e0 = csr[j],     e1 = csr[j + 1], e2 = csr[j + 2], e3 = csr[j + 3];
        int2 e4 = csr[j + 4], e5 = csr[j + 5], e6 = csr[j + 6], e7 = csr[j + 7];
        float v0 = h[e0.x * 64 + lane], v1 = h[e1.x * 64 + lane];
        float v2 = h[e2.x * 64 + lane], v3 = h[e3.x * 64 + lane];
        float v4 = h[e4.x * 64 + lane], v5 = h[e5.x * 64 + lane];
        float v6 = h[e6.x * 64 + lane], v7 = h[e7.x * 64 + lane];
        acc = fmaf(v0, __int_as_float(e0.y), acc);
        acc = fmaf(v1, __int_as_float(e1.y), acc);
        acc = fmaf(v2, __int_as_float(e2.y), acc);
        acc = fmaf(v3, __int_as_float(e3.y), acc);
        acc = fmaf(v4, __int_as_float(e4.y), acc);
        acc = fmaf(v5, __int_as_float(e5.y), acc);
        acc = fmaf(v6, __int_as_float(e6.y), acc);
        acc = fmaf(v7, __int_as_float(e7.y), acc);
    }
    if (j + 3 < end) {
        int2 e0 = csr[j], e1 = csr[j + 1], e2 = csr[j + 2], e3 = csr[j + 3];
        float v0 = h[e0.x * 64 + lane], v1 = h[e1.x * 64 + lane];
        float v2 = h[e2.x * 64 + lane], v3 = h[e3.x * 64 + lane];
        acc = fmaf(v0, __int_as_float(e0.y), acc);
        acc = fmaf(v1, __int_as_float(e1.y), acc);
        acc = fmaf(v2, __int_as_float(e2.y), acc);
        acc = fmaf(v3, __int_as_float(e3.y), acc);
        j += 4;
    }
    for (; j < end; ++j) {
        int2 e = csr[j];
        acc = fmaf(h[e.x * 64 + lane], __int_as_float(e.y), acc);
    }
    srow[wv][lane] = acc;
    __syncthreads();
    float o = b2[lane];
    const float* sr = srow[wv];
#pragma unroll
    for (int k = 0; k < 64; k += 4) {
        float4 s4 = *reinterpret_cast<const float4*>(sr + k);
        o = fmaf(s4.x, W2[(k + 0) * 64 + lane], o);
        o = fmaf(s4.y, W2[(k + 1) * 64 + lane], o);
        o = fmaf(s4.z, W2[(k + 2) * 64 + lane], o);
        o = fmaf(s4.w, W2[(k + 3) * 64 + lane], o);
    }
    out[gid] = fmaxf(o, 0.f);
}

extern "C" void kernel_launch(void* const* d_in, const int* in_sizes, int n_in,
                              void* d_out, int out_size, void* d_ws, size_t ws_size,
                              hipStream_t stream) {
    const float* x  = (const float*)d_in[0];
    const int*   ei = (const int*)d_in[1];   // [2, NE]: src row then dst row
    const float* W1 = (const float*)d_in[2];
    const float* b1 = (const float*)d_in[3];
    const float* W2 = (const float*)d_in[4];
    const float* b2 = (const float*)d_in[5];
    float* out = (float*)d_out;
    const int* src = ei;
    const int* dst = ei + NE;

    char* w = (char*)d_ws;
    auto take = [&](size_t bytes) { char* p = w; w += ALIGN_UP(bytes, 256); return p; };
    int*   cnt    = (int*)  take((size_t)NN * 4);
    float* dinv   = (float*)take((size_t)NN * 4);
    int*   off    = (int*)  take((size_t)(NN + 1) * 4);
    int*   cursor = (int*)  take((size_t)NN * 4);
    int*   bsum   = (int*)  take(256 * 4);
    int*   bofs   = (int*)  take(256 * 4);
    int2*  csr    = (int2*) take((size_t)NE * 8);
    float* h      = (float*)take((size_t)NN * 64 * 4);

    const int NB_SCAN = (NN + 255) / 256;   // 196
    const int NB_EDGE = (NE + 255) / 256;   // 3125
    const int NB_NODE = (NN * 64) / 256;    // 12500 (exact)

    hipMemsetAsync(cnt, 0, (size_t)NN * 4, stream);
    count_deg<<<NB_EDGE, 256, 0, stream>>>(dst, cnt);
    scanA<<<NB_SCAN, 256, 0, stream>>>(cnt, dinv, off, bsum);
    scanB<<<1, 256, 0, stream>>>(bsum, bofs, NB_SCAN);
    scanC<<<NB_SCAN, 256, 0, stream>>>(off, bofs, cursor);
    fill_csr<<<NB_EDGE, 256, 0, stream>>>(src, dst, dinv, cursor, csr);

    gcn_layer1<<<NB_NODE, 256, 0, stream>>>(x, off, csr, dinv, W1, b1, h);
    gcn_layer2<<<NB_NODE, 256, 0, stream>>>(h, off, csr, dinv, W2, b2, out);
}